// Round 3
// baseline (244.167 us; speedup 1.0000x reference)
//
#include <hip/hip_runtime.h>
#include <math.h>

#define B_DIM 256
#define T_DIM 8192
#define BLOCK 256
#define NSLOT 256
#define NBLK  1024                       // resident-friendly: 4 blocks/CU
#define ROWS_TOT (B_DIM * T_DIM)         // 2,097,152 rows
#define NTILES (ROWS_TOT / BLOCK)        // 8192 tiles of 256 rows
#define NT_PER (NTILES / NBLK)           // 8 tiles per block
#define NF4  (ROWS_TOT * 3)              // pred/gt f4 count
#define NPH4 (ROWS_TOT * 3 / 4)          // phase f4 count

// Persistent tiles + LDS row staging + async-stage (T14) pipeline.
//  - per tile: stage pred rows R..R+257 (774 f4) and phase rows R..R+256 (193 f4)
//    into LDS with pure unit-stride loads; gt consumed at store time (sse), never staged.
//  - row math (vel/acc/speed/nll/coherence) fully thread-private from LDS rows:
//    no exchanges, no sentinels, 2 barriers/tile.
//  - loads for tile k+1 issued between barrier2(k) and compute(k): latency hides
//    under compute; barriers fence the compiler from sinking them.
// LDS layouts (conflict-free): pred pitch 12 floats -> b128 reads at f4-stride 3
// (gcd(3,8)=1 covers all bank-quads); phase pitch 3 -> scalar stride-3 (2 lanes/bank).
// ws layout: NSLOT x 8 doubles: 0:sse+12*nll 1:coher_sum 2:coher_cnt 3:pen2 4:velsq 5:accsq

struct Stage {
    float4 A0, A1, A2;      // pred f4: tid, tid+256, tid+512
    float4 G0, G1, G2;      // gt   f4: same indices
    float4 At;              // pred tail f4 (tid<6): rows 256,257
    float4 Ph;              // phase f4 (tid<193)
    int    gph;             // gt_phase[R+tid]
};

__device__ __forceinline__ Stage load_tile(int tile, int tid,
    const float4* __restrict__ pred4, const float4* __restrict__ gt4,
    const float4* __restrict__ ph4,   const int* __restrict__ gtp)
{
    Stage st;
    const int R = tile * BLOCK;
    const size_t b4 = (size_t)R * 3;

    st.A0 = pred4[b4 + tid];        st.G0 = gt4[b4 + tid];
    st.A1 = pred4[b4 + tid + 256];  st.G1 = gt4[b4 + tid + 256];
    st.A2 = pred4[b4 + tid + 512];  st.G2 = gt4[b4 + tid + 512];

    if (tid < 6) {                  // rows 256,257 (clamped at global end; masked anyway)
        size_t it4 = b4 + 768 + tid;
        if (it4 > (size_t)(NF4 - 1)) it4 = (size_t)(NF4 - 1);
        st.At = pred4[it4];
    } else {
        st.At = make_float4(0.f, 0.f, 0.f, 0.f);
    }

    const size_t p4 = (size_t)192 * tile;                   // phase f4 base (R*3/4)
    const int phcnt = (p4 + 193 <= (size_t)NPH4) ? 193 : 192;   // last tile: 192
    st.Ph = (tid < phcnt) ? ph4[p4 + tid] : make_float4(0.f, 0.f, 0.f, 0.f);

    st.gph = gtp[R + tid];
    return st;
}

__device__ __forceinline__ float pen_term(float s) {
    float d = fmaxf(sqrtf(s) - 10.0f, 0.0f);
    return d * d;
}
__device__ __forceinline__ void argmax3(float l0, float l1, float l2, int &p, float &m) {
    p = 0; m = l0;
    if (l1 > m) { m = l1; p = 1; }
    if (l2 > m) { m = l2; p = 2; }
}
__device__ __forceinline__ float nll3(float l0, float l1, float l2, int g) {
    float mx = fmaxf(l0, fmaxf(l1, l2));
    float s = __expf(l0 - mx) + __expf(l1 - mx) + __expf(l2 - mx);
    float sel = (g == 0) ? l0 : ((g == 1) ? l1 : l2);
    return mx + __logf(s) - sel;
}

__global__ __launch_bounds__(BLOCK) void combined_loss_main(
    const float4* __restrict__ pred4,
    const float4* __restrict__ ph4,
    const float4* __restrict__ gt4,
    const int*    __restrict__ gt_phase,
    double* __restrict__ ws)
{
    __shared__ float4 s_pred[774];      // 258 rows x 12 floats
    __shared__ float4 s_ph4[194];       // 193 f4 (+pad)
    __shared__ float  s_red[4][6];
    const float* s_ph = (const float*)s_ph4;

    const int tid = threadIdx.x;
    const int blk = blockIdx.x;

    float sse = 0.f, nll = 0.f, csum = 0.f, ccnt = 0.f;
    float pen2 = 0.f, velsq = 0.f, accsq = 0.f;

    Stage cur = load_tile(blk, tid, pred4, gt4, ph4, gt_phase);

    for (int it = 0; it < NT_PER; ++it) {
        const int tile = it * NBLK + blk;

        __syncthreads();                        // previous tile's LDS reads done
        // ---- store staged regs -> LDS; sse f4-elementwise from regs ----
        s_pred[tid]       = cur.A0;
        s_pred[tid + 256] = cur.A1;
        s_pred[tid + 512] = cur.A2;
        if (tid < 6)   s_pred[768 + tid] = cur.At;
        if (tid < 193) s_ph4[tid] = cur.Ph;
        {
            float d;
            d = cur.A0.x - cur.G0.x; sse = fmaf(d, d, sse);
            d = cur.A0.y - cur.G0.y; sse = fmaf(d, d, sse);
            d = cur.A0.z - cur.G0.z; sse = fmaf(d, d, sse);
            d = cur.A0.w - cur.G0.w; sse = fmaf(d, d, sse);
            d = cur.A1.x - cur.G1.x; sse = fmaf(d, d, sse);
            d = cur.A1.y - cur.G1.y; sse = fmaf(d, d, sse);
            d = cur.A1.z - cur.G1.z; sse = fmaf(d, d, sse);
            d = cur.A1.w - cur.G1.w; sse = fmaf(d, d, sse);
            d = cur.A2.x - cur.G2.x; sse = fmaf(d, d, sse);
            d = cur.A2.y - cur.G2.y; sse = fmaf(d, d, sse);
            d = cur.A2.z - cur.G2.z; sse = fmaf(d, d, sse);
            d = cur.A2.w - cur.G2.w; sse = fmaf(d, d, sse);
        }
        const int gph = cur.gph;
        __syncthreads();                        // staged data visible

        // ---- issue next tile's loads (hide under compute below) ----
        Stage nxt;
        if (it + 1 < NT_PER) nxt = load_tile((it + 1) * NBLK + blk, tid, pred4, gt4, ph4, gt_phase);
        else                 nxt = cur;

        // ---- thread-private row math from LDS ----
        const int t  = (tile * BLOCK + tid) & (T_DIM - 1);
        const bool v1 = t < (T_DIM - 1);
        const bool v2 = t < (T_DIM - 2);
        const int l3 = 3 * tid;

        const float4 r0a = s_pred[l3],     r0b = s_pred[l3 + 1], r0c = s_pred[l3 + 2];
        const float4 r1a = s_pred[l3 + 3], r1b = s_pred[l3 + 4], r1c = s_pred[l3 + 5];
        const float4 r2a = s_pred[l3 + 6], r2b = s_pred[l3 + 7], r2c = s_pred[l3 + 8];

        // vel + speed
        {
            const float v0 = r1a.x - r0a.x, v1f = r1a.y - r0a.y, v2f = r1a.z - r0a.z, v3 = r1a.w - r0a.w;
            const float v4 = r1b.x - r0b.x, v5  = r1b.y - r0b.y, v6  = r1b.z - r0b.z, v7 = r1b.w - r0b.w;
            const float v8 = r1c.x - r0c.x, v9  = r1c.y - r0c.y, v10 = r1c.z - r0c.z, v11 = r1c.w - r0c.w;
            const float q0 = v0*v0, q1 = v1f*v1f, q2 = v2f*v2f, q3 = v3*v3;
            const float q4 = v4*v4, q5 = v5*v5,   q6 = v6*v6,   q7 = v7*v7;
            const float q8 = v8*v8, q9 = v9*v9,   q10 = v10*v10, q11 = v11*v11;
            if (v1) {
                velsq += (q0+q1+q2+q3) + (q4+q5+q6+q7) + (q8+q9+q10+q11);
                pen2  += pen_term(q0+q1+q2) + pen_term(q3+q4+q5)
                       + pen_term(q6+q7+q8) + pen_term(q9+q10+q11);
            }
        }
        // acc
        if (v2) {
            float a;
            a = r2a.x - 2.0f*r1a.x + r0a.x; accsq = fmaf(a, a, accsq);
            a = r2a.y - 2.0f*r1a.y + r0a.y; accsq = fmaf(a, a, accsq);
            a = r2a.z - 2.0f*r1a.z + r0a.z; accsq = fmaf(a, a, accsq);
            a = r2a.w - 2.0f*r1a.w + r0a.w; accsq = fmaf(a, a, accsq);
            a = r2b.x - 2.0f*r1b.x + r0b.x; accsq = fmaf(a, a, accsq);
            a = r2b.y - 2.0f*r1b.y + r0b.y; accsq = fmaf(a, a, accsq);
            a = r2b.z - 2.0f*r1b.z + r0b.z; accsq = fmaf(a, a, accsq);
            a = r2b.w - 2.0f*r1b.w + r0b.w; accsq = fmaf(a, a, accsq);
            a = r2c.x - 2.0f*r1c.x + r0c.x; accsq = fmaf(a, a, accsq);
            a = r2c.y - 2.0f*r1c.y + r0c.y; accsq = fmaf(a, a, accsq);
            a = r2c.z - 2.0f*r1c.z + r0c.z; accsq = fmaf(a, a, accsq);
            a = r2c.w - 2.0f*r1c.w + r0c.w; accsq = fmaf(a, a, accsq);
        }
        // phase: nll + coherence (both rows thread-private from LDS)
        {
            const float p00 = s_ph[l3], p01 = s_ph[l3 + 1], p02 = s_ph[l3 + 2];
            nll += nll3(p00, p01, p02, gph);
            if (v1) {
                const float p10 = s_ph[l3 + 3], p11 = s_ph[l3 + 4], p12 = s_ph[l3 + 5];
                int pP, pN; float mP, mN;
                argmax3(p00, p01, p02, pP, mP);
                argmax3(p10, p11, p12, pN, mN);
                const int mask = (pP == 0) ? 4 : ((pP == 1) ? 1 : 3);  // illegal: (0,2),(1,0),(2,0),(2,1)
                if ((mask >> pN) & 1) { csum += mN * mN; ccnt += 1.f; }
            }
        }

        cur = nxt;
    }

    // ---- reduce: 6 chains (sse + 12*nll folded: /(B*T) == 12/(B*T*12)) ----
    float vals[6] = { fmaf(12.0f, nll, sse), csum, ccnt, pen2, velsq, accsq };
    #pragma unroll
    for (int off = 32; off > 0; off >>= 1) {
        #pragma unroll
        for (int q = 0; q < 6; ++q)
            vals[q] += __shfl_down(vals[q], off, 64);
    }
    const int wave = tid >> 6, lane = tid & 63;
    if (lane == 0) {
        #pragma unroll
        for (int q = 0; q < 6; ++q) s_red[wave][q] = vals[q];
    }
    __syncthreads();
    if (tid < 6) {
        const double acc = (double)s_red[0][tid] + (double)s_red[1][tid]
                         + (double)s_red[2][tid] + (double)s_red[3][tid];
        atomicAdd(&ws[(size_t)(blk & (NSLOT - 1)) * 8 + tid], acc);
    }
}

__global__ __launch_bounds__(256) void combined_loss_final(
    const double* __restrict__ ws, float* __restrict__ out)
{
    __shared__ double sred[4][6];
    const int tid = threadIdx.x;
    double v[6];
    #pragma unroll
    for (int q = 0; q < 6; ++q) v[q] = ws[(size_t)tid * 8 + q];
    #pragma unroll
    for (int off = 32; off > 0; off >>= 1) {
        #pragma unroll
        for (int q = 0; q < 6; ++q)
            v[q] += __shfl_down(v[q], off, 64);
    }
    const int wave = tid >> 6, lane = tid & 63;
    if (lane == 0) {
        #pragma unroll
        for (int q = 0; q < 6; ++q) sred[wave][q] = v[q];
    }
    __syncthreads();
    if (tid == 0) {
        double s[6];
        #pragma unroll
        for (int q = 0; q < 6; ++q)
            s[q] = sred[0][q] + sred[1][q] + sred[2][q] + sred[3][q];
        const double robot_phase = s[0] / (double)((size_t)B_DIM * T_DIM * 12);
        const double coher = (s[2] > 0.0) ? (s[1] / fmax(s[2], 1.0)) : 0.0;
        const double speed = 5.0  * (s[3] / (double)((size_t)B_DIM * (T_DIM - 1) * 4));
        const double vel   = 0.05 * (s[4] / (double)((size_t)B_DIM * (T_DIM - 1) * 12));
        const double acc   = 0.01 * (s[5] / (double)((size_t)B_DIM * (T_DIM - 2) * 12));
        out[0] = (float)(robot_phase + 10.0 * coher + speed + vel + acc);
    }
}

extern "C" void kernel_launch(void* const* d_in, const int* in_sizes, int n_in,
                              void* d_out, int out_size, void* d_ws, size_t ws_size,
                              hipStream_t stream)
{
    const float4* pred4      = (const float4*)d_in[0];
    const float4* ph4        = (const float4*)d_in[1];
    const float4* gt4        = (const float4*)d_in[2];
    const int*    gt_phase   = (const int*)d_in[3];
    double* ws  = (double*)d_ws;
    float*  out = (float*)d_out;

    hipMemsetAsync(d_ws, 0, (size_t)NSLOT * 8 * sizeof(double), stream);

    combined_loss_main<<<dim3(NBLK), BLOCK, 0, stream>>>(pred4, ph4, gt4, gt_phase, ws);
    combined_loss_final<<<1, 256, 0, stream>>>(ws, out);
}

// Round 4
// 241.416 us; speedup vs baseline: 1.0114x; 1.0114x over previous
//
#include <hip/hip_runtime.h>
#include <math.h>

#define B_DIM 256
#define T_DIM 8192
#define BLOCK 256
#define NSLOT 256
#define ROWS_TOT (B_DIM * T_DIM)
#define NF4  (ROWS_TOT * 3)              // 6,291,456 pred/gt f4
#define NPH4 (NF4 / 4)                   // 1,572,864 phase f4
#define K_PRED 2
#define NPB (BLOCK * K_PRED)             // 512 pred f4 per pred-block
#define NB_PRED (NF4 / NPB)              // 12288 pred blocks
#define NB_PH   (NPH4 / BLOCK)           // 6144 phase blocks
#define GRID_BLOCKS (NB_PRED + NB_PH)

// Discriminating experiment: occupancy(100%) x per-wave load batch (8 f4) SIMULTANEOUSLY.
// Role-split blocks so each path stays under the 64-VGPR bound of __launch_bounds__(256,8):
//  - pred path: thread-per-f4, K=2, 8 independent coalesced f4 loads batched up front;
//    sse/vel/acc elementwise, speed via round-1 carry LDS exchange.
//  - phase path: round-1 verified nll/coherence code (zw + argmax LDS exchange).
// ws layout: NSLOT x 8 doubles: 0:sse+12*nll 1:coher_sum 2:coher_cnt 3:pen2 4:velsq 5:accsq

__device__ __forceinline__ unsigned div3u(unsigned x) {
    return __umulhi(x, 0xAAAAAAABu) >> 1;          // exact x/3 for all uint32
}
__device__ __forceinline__ float pen_term(float s) {
    float d = fmaxf(sqrtf(s) - 10.0f, 0.0f);
    return d * d;
}
__device__ __forceinline__ void argmax3(float l0, float l1, float l2, int &p, float &m) {
    p = 0; m = l0;
    if (l1 > m) { m = l1; p = 1; }
    if (l2 > m) { m = l2; p = 2; }
}
__device__ __forceinline__ float nll3(float l0, float l1, float l2, int g) {
    float mx = fmaxf(l0, fmaxf(l1, l2));
    float s = __expf(l0 - mx) + __expf(l1 - mx) + __expf(l2 - mx);
    float sel = (g == 0) ? l0 : ((g == 1) ? l1 : l2);
    return mx + __logf(s) - sel;
}

__device__ __forceinline__ void reduce_and_emit(float vals[6], int tid, int blk,
                                                float s_red[4][6], double* ws)
{
    #pragma unroll
    for (int off = 32; off > 0; off >>= 1) {
        #pragma unroll
        for (int q = 0; q < 6; ++q)
            vals[q] += __shfl_down(vals[q], off, 64);
    }
    const int wave = tid >> 6, lane = tid & 63;
    if (lane == 0) {
        #pragma unroll
        for (int q = 0; q < 6; ++q) s_red[wave][q] = vals[q];
    }
    __syncthreads();
    if (tid < 6) {
        const double acc = (double)s_red[0][tid] + (double)s_red[1][tid]
                         + (double)s_red[2][tid] + (double)s_red[3][tid];
        atomicAdd(&ws[(size_t)(blk & (NSLOT - 1)) * 8 + tid], acc);
    }
}

__global__ __launch_bounds__(BLOCK, 8) void combined_loss_main(
    const float4* __restrict__ pred4,
    const float4* __restrict__ ph4,
    const float4* __restrict__ gt4,
    const int*    __restrict__ gt_phase,
    double* __restrict__ ws)
{
    __shared__ float s_xchg[NPB + 1];       // pred: carry; phase: reused as pm_m
    __shared__ float s_red[4][6];

    const int tid = threadIdx.x;
    const int blk = blockIdx.x;

    if (blk < NB_PRED) {
        // ======================= PRED PATH =======================
        const unsigned base = (unsigned)blk * NPB;

        // -- carry sentinel (tid 0): first f4 of next block's range, issued first --
        float4 Ab = make_float4(0.f,0.f,0.f,0.f), Ab3 = Ab;
        unsigned cb = 0; bool carry_sent = false;
        if (tid == 0) {
            const unsigned ib = base + NPB;
            if (ib < (unsigned)NF4) {
                const unsigned rb = div3u(ib);
                cb = ib - 3u * rb;
                if ((rb & (T_DIM - 1)) < (T_DIM - 1)) {
                    carry_sent = true;
                    Ab  = pred4[ib];
                    Ab3 = pred4[ib + 3u];
                }
            }
        }

        // -- batched loads: 8 independent f4, addresses first, then loads --
        unsigned idx[K_PRED], i3[K_PRED], i6[K_PRED], cc[K_PRED];
        bool vv1[K_PRED], vv2[K_PRED];
        #pragma unroll
        for (int k = 0; k < K_PRED; ++k) {
            const unsigned i = base + (unsigned)(k * BLOCK) + tid;
            const unsigned r = div3u(i);
            cc[k] = i - 3u * r;
            const unsigned t = r & (T_DIM - 1);
            vv1[k] = t < (T_DIM - 1);
            vv2[k] = t < (T_DIM - 2);
            idx[k] = i;
            i3[k] = vv1[k] ? i + 3u : i;
            i6[k] = vv2[k] ? i + 6u : i;
        }
        float4 A[K_PRED], G[K_PRED], A3[K_PRED], A6[K_PRED];
        #pragma unroll
        for (int k = 0; k < K_PRED; ++k) {
            A[k]  = pred4[idx[k]];
            G[k]  = gt4[idx[k]];
            A3[k] = pred4[i3[k]];
            A6[k] = pred4[i6[k]];
        }

        // -- elementwise math --
        float sse = 0.f, velsq = 0.f, accsq = 0.f;
        float loc[K_PRED], car[K_PRED];
        #pragma unroll
        for (int k = 0; k < K_PRED; ++k) {
            float d;
            d = A[k].x - G[k].x; sse = fmaf(d, d, sse);
            d = A[k].y - G[k].y; sse = fmaf(d, d, sse);
            d = A[k].z - G[k].z; sse = fmaf(d, d, sse);
            d = A[k].w - G[k].w; sse = fmaf(d, d, sse);

            float sqx = 0.f, sqy = 0.f, sqz = 0.f, sqw = 0.f;
            if (vv1[k]) {
                const float vx = A3[k].x - A[k].x, vy = A3[k].y - A[k].y;
                const float vz = A3[k].z - A[k].z, vw = A3[k].w - A[k].w;
                sqx = vx * vx; sqy = vy * vy; sqz = vz * vz; sqw = vw * vw;
                velsq += sqx + sqy + sqz + sqw;
            }
            if (vv2[k]) {
                float a;
                a = A6[k].x - 2.0f * A3[k].x + A[k].x; accsq = fmaf(a, a, accsq);
                a = A6[k].y - 2.0f * A3[k].y + A[k].y; accsq = fmaf(a, a, accsq);
                a = A6[k].z - 2.0f * A3[k].z + A[k].z; accsq = fmaf(a, a, accsq);
                a = A6[k].w - 2.0f * A3[k].w + A[k].w; accsq = fmaf(a, a, accsq);
            }
            // speed pieces: s0=xyz(c0) s1=w(c0)+xy(c1) s2=zw(c1)+x(c2) s3=yzw(c2)
            float l3v, crv;
            const unsigned c = cc[k];
            if (c == 0)      { l3v = sqx + sqy + sqz; crv = sqw; }
            else if (c == 1) { l3v = sqz + sqw;       crv = sqx + sqy; }
            else             { l3v = sqy + sqz + sqw; crv = sqx; }
            loc[k] = l3v; car[k] = crv;
            s_xchg[k * BLOCK + tid] = crv;
        }
        if (tid == 0) {
            float crs = 0.f;
            if (carry_sent) {
                const float bx = Ab3.x - Ab.x, by = Ab3.y - Ab.y;
                const float bz = Ab3.z - Ab.z, bw = Ab3.w - Ab.w;
                const float sx = bx * bx, sy = by * by, sw = bw * bw;
                (void)bz;
                crs = (cb == 0) ? sw : ((cb == 1) ? (sx + sy) : sx);
            }
            s_xchg[NPB] = crs;
        }
        __syncthreads();

        // -- speed: local3 + neighbor carry --
        float pen2 = 0.f;
        #pragma unroll
        for (int k = 0; k < K_PRED; ++k) {
            const unsigned ck = cc[k];
            const float up = s_xchg[k * BLOCK + tid + 1];
            const float a = loc[k] + ((ck == 1u) ? up : 0.f);   // c0:s0  c1:s2  c2:s3
            const float b = (ck == 0u) ? (car[k] + up) : 0.f;   // c0:s1
            pen2 += pen_term(a) + pen_term(b);
        }
        __syncthreads();    // s_xchg reads done before reduce reuses LDS region

        float vals[6] = { sse, 0.f, 0.f, pen2, velsq, accsq };
        reduce_and_emit(vals, tid, blk, s_red, ws);

    } else {
        // ======================= PHASE PATH =======================
        float2* s_zw  = (float2*)s_xchg;                 // [BLOCK+1]
        float*  s_pm_m = s_xchg;                         // reused after barrier
        __shared__ int s_pm_p[BLOCK + 1];

        const int pblk = blk - NB_PRED;
        const unsigned j = (unsigned)pblk * BLOCK + tid;     // phase f4 index

        // -- sentinels issued first --
        float2 zwp_s = make_float2(0.f, 0.f);
        if (tid == 0 && j != 0) zwp_s = ((const float2*)ph4)[2u * j - 1u];
        float4 Pn = make_float4(0.f,0.f,0.f,0.f);
        bool pn_valid = false;
        if (tid == BLOCK - 1 && j + 1u < (unsigned)NPH4) { pn_valid = true; Pn = ph4[j + 1u]; }

        const float4 P = ph4[j];
        const unsigned g   = div3u(j);
        const unsigned dph = j - 3u * g;
        const unsigned prow = 4u * g + dph;
        int gA, gB = 0;
        if (dph == 2) {
            const int2 gg = ((const int2*)gt_phase)[prow >> 1];   // prow even for dph==2
            gA = gg.x; gB = gg.y;
        } else {
            gA = gt_phase[prow];
        }

        s_zw[tid + 1] = make_float2(P.z, P.w);
        if (tid == 0) s_zw[0] = zwp_s;
        __syncthreads();    // zw visible

        const float2 zwp = s_zw[tid];
        float l0, l1, l2;
        if (dph == 0)      { l0 = P.x;   l1 = P.y;   l2 = P.z; }
        else if (dph == 1) { l0 = zwp.y; l1 = P.x;   l2 = P.y; }
        else               { l0 = zwp.x; l1 = zwp.y; l2 = P.x; }

        float nll = nll3(l0, l1, l2, gA);
        int pP; float mP;
        argmax3(l0, l1, l2, pP, mP);

        int p3 = 0; float m3 = 0.f;
        if (dph == 2) {                      // second, fully-local row (y,z,w)
            nll += nll3(P.y, P.z, P.w, gB);
            argmax3(P.y, P.z, P.w, p3, m3);
        }
        __syncthreads();    // zw reads done; s_xchg reusable as pm_m
        s_pm_m[tid] = mP; s_pm_p[tid] = pP;
        if (tid == BLOCK - 1) {
            float mS = 0.f; int pS = 0;
            if (pn_valid) {
                const unsigned jn = j + 1u;
                const unsigned gn = div3u(jn);
                const unsigned dn = jn - 3u * gn;
                float a0, a1, a2;
                if (dn == 0)      { a0 = Pn.x; a1 = Pn.y; a2 = Pn.z; }
                else if (dn == 1) { a0 = P.w;  a1 = Pn.x; a2 = Pn.y; }
                else              { a0 = P.z;  a1 = P.w;  a2 = Pn.x; }
                argmax3(a0, a1, a2, pS, mS);
            }
            s_pm_m[BLOCK] = mS; s_pm_p[BLOCK] = pS;
        }
        __syncthreads();    // pm visible

        float csum = 0.f, ccnt = 0.f;
        {
            const float mN = s_pm_m[tid + 1];
            const int   pN = s_pm_p[tid + 1];
            const unsigned t1 = prow & (T_DIM - 1);
            if (t1 < (T_DIM - 1)) {                       // pair (prow, prow+1)
                const int   pB2 = (dph == 2) ? p3 : pN;
                const float mB2 = (dph == 2) ? m3 : mN;
                const int mask = (pP == 0) ? 4 : ((pP == 1) ? 1 : 3);
                if ((mask >> pB2) & 1) { csum += mB2 * mB2; ccnt += 1.f; }
            }
            if (dph == 2) {                               // pair (prow+1, prow+2)
                const unsigned t2 = (prow + 1u) & (T_DIM - 1);
                if (t2 < (T_DIM - 1)) {
                    const int mask = (p3 == 0) ? 4 : ((p3 == 1) ? 1 : 3);
                    if ((mask >> pN) & 1) { csum += mN * mN; ccnt += 1.f; }
                }
            }
        }
        __syncthreads();    // pm reads done before reduce reuses LDS region

        float vals[6] = { 12.0f * nll, csum, ccnt, 0.f, 0.f, 0.f };
        reduce_and_emit(vals, tid, blk, s_red, ws);
    }
}

__global__ __launch_bounds__(256) void combined_loss_final(
    const double* __restrict__ ws, float* __restrict__ out)
{
    __shared__ double sred[4][6];
    const int tid = threadIdx.x;
    double v[6];
    #pragma unroll
    for (int q = 0; q < 6; ++q) v[q] = ws[(size_t)tid * 8 + q];
    #pragma unroll
    for (int off = 32; off > 0; off >>= 1) {
        #pragma unroll
        for (int q = 0; q < 6; ++q)
            v[q] += __shfl_down(v[q], off, 64);
    }
    const int wave = tid >> 6, lane = tid & 63;
    if (lane == 0) {
        #pragma unroll
        for (int q = 0; q < 6; ++q) sred[wave][q] = v[q];
    }
    __syncthreads();
    if (tid == 0) {
        double s[6];
        #pragma unroll
        for (int q = 0; q < 6; ++q)
            s[q] = sred[0][q] + sred[1][q] + sred[2][q] + sred[3][q];
        const double robot_phase = s[0] / (double)((size_t)B_DIM * T_DIM * 12);
        const double coher = (s[2] > 0.0) ? (s[1] / fmax(s[2], 1.0)) : 0.0;
        const double speed = 5.0  * (s[3] / (double)((size_t)B_DIM * (T_DIM - 1) * 4));
        const double vel   = 0.05 * (s[4] / (double)((size_t)B_DIM * (T_DIM - 1) * 12));
        const double acc   = 0.01 * (s[5] / (double)((size_t)B_DIM * (T_DIM - 2) * 12));
        out[0] = (float)(robot_phase + 10.0 * coher + speed + vel + acc);
    }
}

extern "C" void kernel_launch(void* const* d_in, const int* in_sizes, int n_in,
                              void* d_out, int out_size, void* d_ws, size_t ws_size,
                              hipStream_t stream)
{
    const float4* pred4      = (const float4*)d_in[0];
    const float4* ph4        = (const float4*)d_in[1];
    const float4* gt4        = (const float4*)d_in[2];
    const int*    gt_phase   = (const int*)d_in[3];
    double* ws  = (double*)d_ws;
    float*  out = (float*)d_out;

    hipMemsetAsync(d_ws, 0, (size_t)NSLOT * 8 * sizeof(double), stream);

    combined_loss_main<<<dim3(GRID_BLOCKS), BLOCK, 0, stream>>>(pred4, ph4, gt4, gt_phase, ws);
    combined_loss_final<<<1, 256, 0, stream>>>(ws, out);
}